// Round 11
// baseline (7185.478 us; speedup 1.0000x reference)
//
#include <hip/hip_runtime.h>
#include <hip/hip_bf16.h>

#define Bdim 64
#define Sdim 2048
#define Hdim 256

typedef __attribute__((ext_vector_type(8))) short short8;
typedef __attribute__((ext_vector_type(4))) float f32x4;

static __device__ __forceinline__ unsigned short f2bf(float f) {
  union { float f; unsigned int u; } v; v.f = f;
  unsigned int r = v.u + 0x7fffu + ((v.u >> 16) & 1u);  // RNE
  return (unsigned short)(r >> 16);
}
static __device__ __forceinline__ float bf2f(unsigned short u) {
  union { unsigned int u; float f; } v; v.u = ((unsigned int)u) << 16;
  return v.f;
}
static __device__ __forceinline__ float bflo(unsigned int u) {
  union { unsigned int u; float f; } v; v.u = u << 16; return v.f;
}
static __device__ __forceinline__ float bfhi(unsigned int u) {
  union { unsigned int u; float f; } v; v.u = u & 0xffff0000u; return v.f;
}

#if __has_builtin(__builtin_amdgcn_rcpf)
#define FAST_RCP(x) __builtin_amdgcn_rcpf(x)
#else
#define FAST_RCP(x) (1.0f / (x))
#endif

// tanh(x) = 1 - 2/(1 + e^{2x}) : 5 ops, saturates correctly at +/-inf.
static __device__ __forceinline__ float tanh_fast(float x) {
  float e = exp2f(x * 2.8853900817779268f);  // e^{2x}
  return 1.0f - 2.0f * FAST_RCP(1.0f + e);
}

#define STEP_BAR() do { __builtin_amdgcn_sched_barrier(0); \
    asm volatile("s_waitcnt lgkmcnt(0)" ::: "memory"); \
    __builtin_amdgcn_s_barrier(); \
    __builtin_amdgcn_sched_barrier(0); } while (0)

// ---------------------------------------------------------------------------
// Phase 2: sequential scan with WAVE ROLE SPECIALIZATION (hardened r10).
// 2 blocks x 768 threads (12 waves); block = 32 batches, groups G0/G1 of 16.
//   M-waves (w=0..3, one per SIMD): W_hh in regs; per phase: ds_read h-tile,
//     32 MFMAs (transposed D = W.h^T), pack acc to bf16 via C++ f2bf
//     (NO inline asm reads MFMA results), ds_write to aT[g].
//   E-waves (w=4..11): per phase: read aT[g'], tanh, cvt_pk (reads tanh
//     outputs only — r6/r7-verified pattern), write h to hG tile + ws2.
// Schedule (each dep crosses exactly one barrier; no same-phase tile sharing):
//   phase A(t): M: acc_G0(t)->aT0 | E: tanh aT1 -> h_G1(t-1)
//   phase B(t): M: acc_G1(t)->aT1 | E: tanh aT0 -> h_G0(t)
// LDS 48KB (ALL zeroed at start): hG[g][buf] = g*16384+buf*8192;
// aT[g] = 32768+g*8192. Fragment packings / swizzles / D-layout are the
// device-verified r6/r7 conventions. Barriers are lgkm-only.
// ---------------------------------------------------------------------------
__global__ __launch_bounds__(768, 1) void rnn_scan_spec(
    const unsigned short* __restrict__ xw1,   // bf16 xw [B][S][H]
    const float* __restrict__ Whh,
    unsigned short* __restrict__ ws2,         // bf16 h history [B][S][H]
    float* __restrict__ hfin) {
  __shared__ __align__(16) char lds[49152];
  const int tid = threadIdx.x;
  const int lane = tid & 63;
  const int w = tid >> 6;          // 0..11
  const int l15 = lane & 15;       // batch-in-group (D col) / W-row selector
  const int g4 = lane >> 4;        // 0..3
  const int bs = blockIdx.x * 32;

  {  // zero ALL of LDS (hG tiles: h(-1)=0; aT tiles: no uninit reads ever)
    uint4 z; z.x = z.y = z.z = z.w = 0u;
    for (int i = tid; i < 3072; i += 768) ((uint4*)lds)[i] = z;
  }
  __syncthreads();

  if (w < 4) {
    // ================= M-waves =================
    short8 wfrag[4][8];     // W_hh[n][k], n = w*64+tau*16+l15, k = ks*32+g4*8+e
#pragma unroll
    for (int tau = 0; tau < 4; ++tau) {
      int n = w * 64 + tau * 16 + l15;
#pragma unroll
      for (int ks = 0; ks < 8; ++ks) {
        int k0 = ks * 32 + g4 * 8;
        const float* p = Whh + n * 256 + k0;
        short8 v;
#pragma unroll
        for (int e = 0; e < 8; ++e) v[e] = (short)f2bf(p[e]);
        wfrag[tau][ks] = v;
      }
    }
    int aroff[8];
#pragma unroll
    for (int ks = 0; ks < 8; ++ks)
      aroff[ks] = l15 * 512 + ((ks * 64 + g4 * 16) ^ ((l15 & 7) << 4));
    int nb[4], wo[4];
#pragma unroll
    for (int tau = 0; tau < 4; ++tau) {
      nb[tau] = w * 64 + tau * 16 + g4 * 4;
      wo[tau] = l15 * 512 + ((2 * nb[tau]) ^ ((l15 & 7) << 4));
    }
    const long xb0 = (long)(bs + l15) * Sdim * Hdim;
    const long xb1 = (long)(bs + 16 + l15) * Sdim * Hdim;

    uint2 cur0[4], cur1[4], nxt[4];
#pragma unroll
    for (int tau = 0; tau < 4; ++tau) {
      cur0[tau] = *(const uint2*)(xw1 + xb0 + nb[tau]);
      cur1[tau] = *(const uint2*)(xw1 + xb1 + nb[tau]);
    }

    for (int t = 0; t < Sdim; ++t) {
      // ---- phase A: acc_G0(t) -> aT0 ----
      {
        if (t + 1 < Sdim) {
#pragma unroll
          for (int tau = 0; tau < 4; ++tau)
            nxt[tau] = *(const uint2*)(xw1 + xb0 + (long)(t + 1) * Hdim + nb[tau]);
        }
        f32x4 acc[4];
#pragma unroll
        for (int tau = 0; tau < 4; ++tau) {
          acc[tau][0] = bflo(cur0[tau].x); acc[tau][1] = bfhi(cur0[tau].x);
          acc[tau][2] = bflo(cur0[tau].y); acc[tau][3] = bfhi(cur0[tau].y);
        }
        const char* hb = lds + ((t + 1) & 1) * 8192;          // hG0[(t-1)&1]
#pragma unroll
        for (int ks = 0; ks < 8; ++ks) {
          short8 h8 = *(const short8*)(hb + aroff[ks]);
#pragma unroll
          for (int tau = 0; tau < 4; ++tau)
            acc[tau] = __builtin_amdgcn_mfma_f32_16x16x32_bf16(wfrag[tau][ks], h8, acc[tau], 0, 0, 0);
        }
        char* at = lds + 32768;                               // aT0
#pragma unroll
        for (int tau = 0; tau < 4; ++tau) {
          unsigned int px = (unsigned int)f2bf(acc[tau][0]) | ((unsigned int)f2bf(acc[tau][1]) << 16);
          unsigned int py = (unsigned int)f2bf(acc[tau][2]) | ((unsigned int)f2bf(acc[tau][3]) << 16);
          *(uint2*)(at + wo[tau]) = make_uint2(px, py);
          cur0[tau] = nxt[tau];
        }
      }
      STEP_BAR();
      // ---- phase B: acc_G1(t) -> aT1 ----
      {
        if (t + 1 < Sdim) {
#pragma unroll
          for (int tau = 0; tau < 4; ++tau)
            nxt[tau] = *(const uint2*)(xw1 + xb1 + (long)(t + 1) * Hdim + nb[tau]);
        }
        f32x4 acc[4];
#pragma unroll
        for (int tau = 0; tau < 4; ++tau) {
          acc[tau][0] = bflo(cur1[tau].x); acc[tau][1] = bfhi(cur1[tau].x);
          acc[tau][2] = bflo(cur1[tau].y); acc[tau][3] = bfhi(cur1[tau].y);
        }
        const char* hb = lds + 16384 + ((t + 1) & 1) * 8192;  // hG1[(t-1)&1]
#pragma unroll
        for (int ks = 0; ks < 8; ++ks) {
          short8 h8 = *(const short8*)(hb + aroff[ks]);
#pragma unroll
          for (int tau = 0; tau < 4; ++tau)
            acc[tau] = __builtin_amdgcn_mfma_f32_16x16x32_bf16(wfrag[tau][ks], h8, acc[tau], 0, 0, 0);
        }
        char* at = lds + 32768 + 8192;                        // aT1
#pragma unroll
        for (int tau = 0; tau < 4; ++tau) {
          unsigned int px = (unsigned int)f2bf(acc[tau][0]) | ((unsigned int)f2bf(acc[tau][1]) << 16);
          unsigned int py = (unsigned int)f2bf(acc[tau][2]) | ((unsigned int)f2bf(acc[tau][3]) << 16);
          *(uint2*)(at + wo[tau]) = make_uint2(px, py);
          cur1[tau] = nxt[tau];
        }
      }
      STEP_BAR();
    }
  } else {
    // ================= E-waves =================
    const int we = w - 4;            // 0..7, owns n = we*32..+31
    int nbE[2], ro[2];
#pragma unroll
    for (int tau = 0; tau < 2; ++tau) {
      nbE[tau] = we * 32 + tau * 16 + g4 * 4;
      ro[tau] = l15 * 512 + ((2 * nbE[tau]) ^ ((l15 & 7) << 4));
    }
    const long ob0 = (long)(bs + l15) * Sdim * Hdim;
    const long ob1 = (long)(bs + 16 + l15) * Sdim * Hdim;

    auto epi = [&](int g, int te) {
      const char* at = lds + 32768 + g * 8192;
      char* hw = lds + g * 16384 + (te & 1) * 8192;
      const long ob = g ? ob1 : ob0;
      const int bb = bs + g * 16 + l15;
#pragma unroll
      for (int tau = 0; tau < 2; ++tau) {
        uint2 q = *(const uint2*)(at + ro[tau]);
        f32x4 v;
        v[0] = tanh_fast(bflo(q.x)); v[1] = tanh_fast(bfhi(q.x));
        v[2] = tanh_fast(bflo(q.y)); v[3] = tanh_fast(bfhi(q.y));
        uint2 p;
        asm("v_cvt_pk_bf16_f32 %0, %1, %2" : "=v"(p.x) : "v"(v[0]), "v"(v[1]));
        asm("v_cvt_pk_bf16_f32 %0, %1, %2" : "=v"(p.y) : "v"(v[2]), "v"(v[3]));
        *(uint2*)(hw + ro[tau]) = p;                            // next MFMA operand
        *(uint2*)(ws2 + ob + (long)te * Hdim + nbE[tau]) = p;   // history for phase 3
        if (te == Sdim - 1)
          *(f32x4*)(hfin + (long)bb * Hdim + nbE[tau]) = v;
      }
    };

    for (int t = 0; t < Sdim; ++t) {
      if (t > 0) epi(1, t - 1);   // finish G1(t-1)  [aT1 from phase B(t-1)]
      STEP_BAR();
      epi(0, t);                  // finish G0(t)    [aT0 from phase A(t)]
      STEP_BAR();
    }
    epi(1, Sdim - 1);             // drain: finish G1(2047)
  }
}

// ---------------------------------------------------------------------------
// Fallback scan (tiny workspace): fused VALU version — known-good from round 3.
// ---------------------------------------------------------------------------
__global__ __launch_bounds__(256, 1) void rnn_scan_valu_fused(
    const float* __restrict__ x, const float* __restrict__ Wih,
    const float* __restrict__ bh, const float* __restrict__ Whh,
    float* __restrict__ hout, float* __restrict__ hfin) {
  __shared__ __align__(16) uint2 wt[64][256];
  __shared__ __align__(16) float hl[256];
  const int n = threadIdx.x;
  const int b = blockIdx.x;
  {
    const float2* src = (const float2*)Whh;
    unsigned int* w32 = (unsigned int*)wt;
    for (int i = n; i < 32768; i += 256) {
      float2 f = src[i];
      unsigned int u = (unsigned int)f2bf(f.x) | ((unsigned int)f2bf(f.y) << 16);
      int row = i >> 7, kk = i & 127, k4 = kk >> 1, half = kk & 1;
      w32[k4 * 512 + row * 2 + half] = u;
    }
  }
  hl[n] = 0.0f;
  __syncthreads();
  const long base = (long)b * Sdim * Hdim + n;
  for (int t = 0; t < Sdim; ++t) {
    const float* xr = x + ((long)b * Sdim + t) * 256;
    const float* wr = Wih + n * 256;
    float acc = bh[n];
    for (int k = 0; k < 256; ++k) acc += xr[k] * wr[k];
#pragma unroll 8
    for (int k4 = 0; k4 < 64; ++k4) {
      uint2 w2 = wt[k4][n];
      float4 h4 = *(const float4*)&hl[k4 * 4];
      acc += bflo(w2.x) * h4.x + bfhi(w2.x) * h4.y
           + bflo(w2.y) * h4.z + bfhi(w2.y) * h4.w;
    }
    float hv = tanh_fast(acc);
    __syncthreads();
    hl[n] = hv;
    hout[base + (long)t * Hdim] = hv;
    if (t == Sdim - 1) hfin[b * Hdim + n] = hv;
    __syncthreads();
  }
}

// ---------------------------------------------------------------------------
// Phases 1 & 3: out[r,n] = A[r,:] @ W[n,:] + bias[n], A is [131072,256].
// 512 thr (8 waves), 128 rows/block; W fully staged in STATIC LDS (bf16,
// XOR-swizzled). A_F32: fp32 vs bf16 A; OUT_F32: fp32 vs bf16 out.
// ---------------------------------------------------------------------------
template<int A_F32, int OUT_F32>
__global__ __launch_bounds__(512, 2) void gemm256(const void* __restrict__ Ap,
                                                  const float* __restrict__ Wf,
                                                  const float* __restrict__ bias,
                                                  void* __restrict__ outp) {
  __shared__ __align__(16) char wl[131072];
  const int tid = threadIdx.x;
  const int lane = tid & 63;
  const int wv = tid >> 6;
  const int l15 = lane & 15;
  const int g = lane >> 4;
  const long r0 = (long)blockIdx.x * 128;

  for (int i = tid; i < 256 * 64; i += 512) {
    int n = i >> 6;
    int kc = (i & 63) * 4;
    f32x4 c = *(const f32x4*)(Wf + n * 256 + kc);
    unsigned int lo = (unsigned int)f2bf(c[0]) | ((unsigned int)f2bf(c[1]) << 16);
    unsigned int hi = (unsigned int)f2bf(c[2]) | ((unsigned int)f2bf(c[3]) << 16);
    int kb = (kc * 2) ^ ((n & 7) << 4);
    unsigned int* dst = (unsigned int*)(wl + n * 512 + kb);
    dst[0] = lo; dst[1] = hi;
  }
  __syncthreads();

  f32x4 acc[16];
#pragma unroll
  for (int tau = 0; tau < 16; ++tau) {
    float bv = bias[tau * 16 + l15];
    acc[tau][0] = bv; acc[tau][1] = bv; acc[tau][2] = bv; acc[tau][3] = bv;
  }

  const long arow = r0 + wv * 16 + l15;
#pragma unroll
  for (int ks = 0; ks < 8; ++ks) {
    const int k0 = ks * 32 + g * 8;
    short8 a;
    if (A_F32) {
      const f32x4* ap = (const f32x4*)((const float*)Ap + arow * 256 + k0);
      f32x4 x0 = ap[0], x1 = ap[1];
#pragma unroll
      for (int e = 0; e < 4; ++e) { a[e] = (short)f2bf(x0[e]); a[4 + e] = (short)f2bf(x1[e]); }
    } else {
      a = *(const short8*)((const unsigned short*)Ap + arow * 256 + k0);
    }
#pragma unroll
    for (int tau = 0; tau < 16; ++tau) {
      int n = tau * 16 + l15;
      int kb = (k0 * 2) ^ ((n & 7) << 4);
      short8 b = *(const short8*)(wl + n * 512 + kb);
      acc[tau] = __builtin_amdgcn_mfma_f32_16x16x32_bf16(a, b, acc[tau], 0, 0, 0);
    }
  }

#pragma unroll
  for (int tau = 0; tau < 16; ++tau) {
    int n = tau * 16 + l15;
#pragma unroll
    for (int e = 0; e < 4; ++e) {
      long row = r0 + wv * 16 + g * 4 + e;
      if (OUT_F32) ((float*)outp)[row * 256 + n] = acc[tau][e];
      else         ((unsigned short*)outp)[row * 256 + n] = f2bf(acc[tau][e]);
    }
  }
}

extern "C" void kernel_launch(void* const* d_in, const int* in_sizes, int n_in,
                              void* d_out, int out_size, void* d_ws, size_t ws_size,
                              hipStream_t stream) {
  const float* x    = (const float*)d_in[0];
  const float* W_ih = (const float*)d_in[1];
  const float* W_hh = (const float*)d_in[2];
  const float* b_h  = (const float*)d_in[3];
  const float* W_ho = (const float*)d_in[4];
  const float* b_o  = (const float*)d_in[5];
  float* out  = (float*)d_out;
  float* hfin = out + (size_t)Bdim * Sdim * Hdim;

  const int gblocks = (Bdim * Sdim) / 128;                    // 1024
  const size_t half = (size_t)Bdim * Sdim * Hdim * 2;         // 64 MiB (bf16 plane)

  if (ws_size >= 2 * half) {
    unsigned short* ws1 = (unsigned short*)d_ws;              // bf16 xw
    unsigned short* ws2 = ws1 + (size_t)Bdim * Sdim * Hdim;   // bf16 h history
    gemm256<1, 0><<<gblocks, 512, 0, stream>>>(x, W_ih, b_h, ws1);   // phase 1
    rnn_scan_spec<<<2, 768, 0, stream>>>(ws1, W_hh, ws2, hfin);      // phase 2
    gemm256<0, 1><<<gblocks, 512, 0, stream>>>(ws2, W_ho, b_o, out); // phase 3
  } else {
    rnn_scan_valu_fused<<<Bdim, 256, 0, stream>>>(x, W_ih, b_h, W_hh, out, hfin);
    gemm256<1, 1><<<gblocks, 512, 0, stream>>>(out, W_ho, b_o, out); // in place
  }
}

// Round 12
// 3607.803 us; speedup vs baseline: 1.9916x; 1.9916x over previous
//
#include <hip/hip_runtime.h>
#include <hip/hip_bf16.h>

#define Bdim 64
#define Sdim 2048
#define Hdim 256

typedef __attribute__((ext_vector_type(8))) short short8;
typedef __attribute__((ext_vector_type(4))) float f32x4;

static __device__ __forceinline__ unsigned short f2bf(float f) {
  union { float f; unsigned int u; } v; v.f = f;
  unsigned int r = v.u + 0x7fffu + ((v.u >> 16) & 1u);  // RNE
  return (unsigned short)(r >> 16);
}
static __device__ __forceinline__ float bf2f(unsigned short u) {
  union { unsigned int u; float f; } v; v.u = ((unsigned int)u) << 16;
  return v.f;
}
static __device__ __forceinline__ float bflo(unsigned int u) {
  union { unsigned int u; float f; } v; v.u = u << 16; return v.f;
}
static __device__ __forceinline__ float bfhi(unsigned int u) {
  union { unsigned int u; float f; } v; v.u = u & 0xffff0000u; return v.f;
}

#if __has_builtin(__builtin_amdgcn_rcpf)
#define FAST_RCP(x) __builtin_amdgcn_rcpf(x)
#else
#define FAST_RCP(x) (1.0f / (x))
#endif

// tanh(x) = 1 - 2/(1 + e^{2x}) : 5 ops, saturates correctly at +/-inf.
static __device__ __forceinline__ float tanh_fast(float x) {
  float e = exp2f(x * 2.8853900817779268f);  // e^{2x}
  return 1.0f - 2.0f * FAST_RCP(1.0f + e);
}

#define STEP_BAR() do { __builtin_amdgcn_sched_barrier(0); \
    asm volatile("s_waitcnt lgkmcnt(0)" ::: "memory"); \
    __builtin_amdgcn_s_barrier(); \
    __builtin_amdgcn_sched_barrier(0); } while (0)

// ---------------------------------------------------------------------------
// Phase 2: sequential scan with WAVE ROLE SPECIALIZATION — 8 waves (r11 had
// 12 waves -> 3 waves/SIMD -> VGPR cap 170 -> wfrag spilled to scratch ->
// 7 ms; now 2 waves/SIMD -> cap 256 >= ~190 needed, wfrag stays resident).
// 2 blocks x 512 threads; block = 32 batches, groups G0/G1 of 16.
//   M-waves (w=0..3, SIMD i%4): W_hh in regs (wfrag[4][8] = 128 VGPR);
//     per phase: 8 ds_read_b128 of h-tile, 32 MFMAs (D = W.h^T), pack acc
//     bf16 via C++ f2bf (NO inline asm on MFMA results), ds_write to aT[g].
//   E-waves (w=4..7, SIMD i%4): each owns 64 n-cols; per phase: read aT[g'],
//     16 tanh/lane, cvt_pk (reads tanh outputs only), write h to hG + ws2.
//   => each SIMD runs 1 M-wave (matrix pipe ~620 cyc) + 1 E-wave
//      (VALU/trans ~360 cyc) CONCURRENTLY.
// Schedule (each dep crosses exactly one barrier; no same-phase tile sharing):
//   phase A(t): M: acc_G0(t)->aT0 | E: tanh aT1 -> h_G1(t-1)
//   phase B(t): M: acc_G1(t)->aT1 | E: tanh aT0 -> h_G0(t)
// LDS 48KB (ALL zeroed): hG[g][buf] = g*16384+buf*8192; aT[g] = 32768+g*8192.
// Fragment packings / swizzles / D-layout = device-verified r6/r7/r11
// conventions. Barriers are lgkm-only.
// ---------------------------------------------------------------------------
__global__ __launch_bounds__(512, 1) void rnn_scan_spec(
    const unsigned short* __restrict__ xw1,   // bf16 xw [B][S][H]
    const float* __restrict__ Whh,
    unsigned short* __restrict__ ws2,         // bf16 h history [B][S][H]
    float* __restrict__ hfin) {
  __shared__ __align__(16) char lds[49152];
  const int tid = threadIdx.x;
  const int lane = tid & 63;
  const int w = tid >> 6;          // 0..7
  const int l15 = lane & 15;       // batch-in-group (D col) / W-row selector
  const int g4 = lane >> 4;        // 0..3
  const int bs = blockIdx.x * 32;

  {  // zero ALL of LDS (hG tiles: h(-1)=0; aT tiles: no uninit reads)
    uint4 z; z.x = z.y = z.z = z.w = 0u;
    for (int i = tid; i < 3072; i += 512) ((uint4*)lds)[i] = z;
  }
  __syncthreads();

  if (w < 4) {
    // ================= M-waves =================
    short8 wfrag[4][8];     // W_hh[n][k], n = w*64+tau*16+l15, k = ks*32+g4*8+e
#pragma unroll
    for (int tau = 0; tau < 4; ++tau) {
      int n = w * 64 + tau * 16 + l15;
#pragma unroll
      for (int ks = 0; ks < 8; ++ks) {
        int k0 = ks * 32 + g4 * 8;
        const float* p = Whh + n * 256 + k0;
        short8 v;
#pragma unroll
        for (int e = 0; e < 8; ++e) v[e] = (short)f2bf(p[e]);
        wfrag[tau][ks] = v;
      }
    }
    int aroff[8];
#pragma unroll
    for (int ks = 0; ks < 8; ++ks)
      aroff[ks] = l15 * 512 + ((ks * 64 + g4 * 16) ^ ((l15 & 7) << 4));
    int nb[4], wo[4];
#pragma unroll
    for (int tau = 0; tau < 4; ++tau) {
      nb[tau] = w * 64 + tau * 16 + g4 * 4;
      wo[tau] = l15 * 512 + ((2 * nb[tau]) ^ ((l15 & 7) << 4));
    }
    const long xb0 = (long)(bs + l15) * Sdim * Hdim;
    const long xb1 = (long)(bs + 16 + l15) * Sdim * Hdim;

    uint2 cur0[4], cur1[4], nxt[4];
#pragma unroll
    for (int tau = 0; tau < 4; ++tau) {
      cur0[tau] = *(const uint2*)(xw1 + xb0 + nb[tau]);
      cur1[tau] = *(const uint2*)(xw1 + xb1 + nb[tau]);
    }

    for (int t = 0; t < Sdim; ++t) {
      // ---- phase A: acc_G0(t) -> aT0 ----
      {
        if (t + 1 < Sdim) {
#pragma unroll
          for (int tau = 0; tau < 4; ++tau)
            nxt[tau] = *(const uint2*)(xw1 + xb0 + (long)(t + 1) * Hdim + nb[tau]);
        }
        f32x4 acc[4];
#pragma unroll
        for (int tau = 0; tau < 4; ++tau) {
          acc[tau][0] = bflo(cur0[tau].x); acc[tau][1] = bfhi(cur0[tau].x);
          acc[tau][2] = bflo(cur0[tau].y); acc[tau][3] = bfhi(cur0[tau].y);
        }
        const char* hb = lds + ((t + 1) & 1) * 8192;          // hG0[(t-1)&1]
#pragma unroll
        for (int ks = 0; ks < 8; ++ks) {
          short8 h8 = *(const short8*)(hb + aroff[ks]);
#pragma unroll
          for (int tau = 0; tau < 4; ++tau)
            acc[tau] = __builtin_amdgcn_mfma_f32_16x16x32_bf16(wfrag[tau][ks], h8, acc[tau], 0, 0, 0);
        }
        char* at = lds + 32768;                               // aT0
#pragma unroll
        for (int tau = 0; tau < 4; ++tau) {
          unsigned int px = (unsigned int)f2bf(acc[tau][0]) | ((unsigned int)f2bf(acc[tau][1]) << 16);
          unsigned int py = (unsigned int)f2bf(acc[tau][2]) | ((unsigned int)f2bf(acc[tau][3]) << 16);
          *(uint2*)(at + wo[tau]) = make_uint2(px, py);
          cur0[tau] = nxt[tau];
        }
      }
      STEP_BAR();
      // ---- phase B: acc_G1(t) -> aT1 ----
      {
        if (t + 1 < Sdim) {
#pragma unroll
          for (int tau = 0; tau < 4; ++tau)
            nxt[tau] = *(const uint2*)(xw1 + xb1 + (long)(t + 1) * Hdim + nb[tau]);
        }
        f32x4 acc[4];
#pragma unroll
        for (int tau = 0; tau < 4; ++tau) {
          acc[tau][0] = bflo(cur1[tau].x); acc[tau][1] = bfhi(cur1[tau].x);
          acc[tau][2] = bflo(cur1[tau].y); acc[tau][3] = bfhi(cur1[tau].y);
        }
        const char* hb = lds + 16384 + ((t + 1) & 1) * 8192;  // hG1[(t-1)&1]
#pragma unroll
        for (int ks = 0; ks < 8; ++ks) {
          short8 h8 = *(const short8*)(hb + aroff[ks]);
#pragma unroll
          for (int tau = 0; tau < 4; ++tau)
            acc[tau] = __builtin_amdgcn_mfma_f32_16x16x32_bf16(wfrag[tau][ks], h8, acc[tau], 0, 0, 0);
        }
        char* at = lds + 32768 + 8192;                        // aT1
#pragma unroll
        for (int tau = 0; tau < 4; ++tau) {
          unsigned int px = (unsigned int)f2bf(acc[tau][0]) | ((unsigned int)f2bf(acc[tau][1]) << 16);
          unsigned int py = (unsigned int)f2bf(acc[tau][2]) | ((unsigned int)f2bf(acc[tau][3]) << 16);
          *(uint2*)(at + wo[tau]) = make_uint2(px, py);
          cur1[tau] = nxt[tau];
        }
      }
      STEP_BAR();
    }
  } else {
    // ================= E-waves (4 waves, 64 n-cols each) =================
    const int we = w - 4;            // 0..3, owns n = we*64..+63
    int nbE[4], ro[4];
#pragma unroll
    for (int tau = 0; tau < 4; ++tau) {
      nbE[tau] = we * 64 + tau * 16 + g4 * 4;
      ro[tau] = l15 * 512 + ((2 * nbE[tau]) ^ ((l15 & 7) << 4));
    }
    const long ob0 = (long)(bs + l15) * Sdim * Hdim;
    const long ob1 = (long)(bs + 16 + l15) * Sdim * Hdim;

    auto epi = [&](int g, int te) {
      const char* at = lds + 32768 + g * 8192;
      char* hw = lds + g * 16384 + (te & 1) * 8192;
      const long ob = g ? ob1 : ob0;
      const int bb = bs + g * 16 + l15;
#pragma unroll
      for (int tau = 0; tau < 4; ++tau) {
        uint2 q = *(const uint2*)(at + ro[tau]);
        f32x4 v;
        v[0] = tanh_fast(bflo(q.x)); v[1] = tanh_fast(bfhi(q.x));
        v[2] = tanh_fast(bflo(q.y)); v[3] = tanh_fast(bfhi(q.y));
        uint2 p;
        asm("v_cvt_pk_bf16_f32 %0, %1, %2" : "=v"(p.x) : "v"(v[0]), "v"(v[1]));
        asm("v_cvt_pk_bf16_f32 %0, %1, %2" : "=v"(p.y) : "v"(v[2]), "v"(v[3]));
        *(uint2*)(hw + ro[tau]) = p;                            // next MFMA operand
        *(uint2*)(ws2 + ob + (long)te * Hdim + nbE[tau]) = p;   // history for phase 3
        if (te == Sdim - 1)
          *(f32x4*)(hfin + (long)bb * Hdim + nbE[tau]) = v;
      }
    };

    for (int t = 0; t < Sdim; ++t) {
      if (t > 0) epi(1, t - 1);   // finish G1(t-1)  [aT1 from phase B(t-1)]
      STEP_BAR();
      epi(0, t);                  // finish G0(t)    [aT0 from phase A(t)]
      STEP_BAR();
    }
    epi(1, Sdim - 1);             // drain: finish G1(2047)
  }
}

// ---------------------------------------------------------------------------
// Fallback scan (tiny workspace): fused VALU version — known-good from round 3.
// ---------------------------------------------------------------------------
__global__ __launch_bounds__(256, 1) void rnn_scan_valu_fused(
    const float* __restrict__ x, const float* __restrict__ Wih,
    const float* __restrict__ bh, const float* __restrict__ Whh,
    float* __restrict__ hout, float* __restrict__ hfin) {
  __shared__ __align__(16) uint2 wt[64][256];
  __shared__ __align__(16) float hl[256];
  const int n = threadIdx.x;
  const int b = blockIdx.x;
  {
    const float2* src = (const float2*)Whh;
    unsigned int* w32 = (unsigned int*)wt;
    for (int i = n; i < 32768; i += 256) {
      float2 f = src[i];
      unsigned int u = (unsigned int)f2bf(f.x) | ((unsigned int)f2bf(f.y) << 16);
      int row = i >> 7, kk = i & 127, k4 = kk >> 1, half = kk & 1;
      w32[k4 * 512 + row * 2 + half] = u;
    }
  }
  hl[n] = 0.0f;
  __syncthreads();
  const long base = (long)b * Sdim * Hdim + n;
  for (int t = 0; t < Sdim; ++t) {
    const float* xr = x + ((long)b * Sdim + t) * 256;
    const float* wr = Wih + n * 256;
    float acc = bh[n];
    for (int k = 0; k < 256; ++k) acc += xr[k] * wr[k];
#pragma unroll 8
    for (int k4 = 0; k4 < 64; ++k4) {
      uint2 w2 = wt[k4][n];
      float4 h4 = *(const float4*)&hl[k4 * 4];
      acc += bflo(w2.x) * h4.x + bfhi(w2.x) * h4.y
           + bflo(w2.y) * h4.z + bfhi(w2.y) * h4.w;
    }
    float hv = tanh_fast(acc);
    __syncthreads();
    hl[n] = hv;
    hout[base + (long)t * Hdim] = hv;
    if (t == Sdim - 1) hfin[b * Hdim + n] = hv;
    __syncthreads();
  }
}

// ---------------------------------------------------------------------------
// Phases 1 & 3: out[r,n] = A[r,:] @ W[n,:] + bias[n], A is [131072,256].
// 512 thr (8 waves), 128 rows/block; W fully staged in STATIC LDS (bf16,
// XOR-swizzled). A_F32: fp32 vs bf16 A; OUT_F32: fp32 vs bf16 out.
// ---------------------------------------------------------------------------
template<int A_F32, int OUT_F32>
__global__ __launch_bounds__(512, 2) void gemm256(const void* __restrict__ Ap,
                                                  const float* __restrict__ Wf,
                                                  const float* __restrict__ bias,
                                                  void* __restrict__ outp) {
  __shared__ __align__(16) char wl[131072];
  const int tid = threadIdx.x;
  const int lane = tid & 63;
  const int wv = tid >> 6;
  const int l15 = lane & 15;
  const int g = lane >> 4;
  const long r0 = (long)blockIdx.x * 128;

  for (int i = tid; i < 256 * 64; i += 512) {
    int n = i >> 6;
    int kc = (i & 63) * 4;
    f32x4 c = *(const f32x4*)(Wf + n * 256 + kc);
    unsigned int lo = (unsigned int)f2bf(c[0]) | ((unsigned int)f2bf(c[1]) << 16);
    unsigned int hi = (unsigned int)f2bf(c[2]) | ((unsigned int)f2bf(c[3]) << 16);
    int kb = (kc * 2) ^ ((n & 7) << 4);
    unsigned int* dst = (unsigned int*)(wl + n * 512 + kb);
    dst[0] = lo; dst[1] = hi;
  }
  __syncthreads();

  f32x4 acc[16];
#pragma unroll
  for (int tau = 0; tau < 16; ++tau) {
    float bv = bias[tau * 16 + l15];
    acc[tau][0] = bv; acc[tau][1] = bv; acc[tau][2] = bv; acc[tau][3] = bv;
  }

  const long arow = r0 + wv * 16 + l15;
#pragma unroll
  for (int ks = 0; ks < 8; ++ks) {
    const int k0 = ks * 32 + g * 8;
    short8 a;
    if (A_F32) {
      const f32x4* ap = (const f32x4*)((const float*)Ap + arow * 256 + k0);
      f32x4 x0 = ap[0], x1 = ap[1];
#pragma unroll
      for (int e = 0; e < 4; ++e) { a[e] = (short)f2bf(x0[e]); a[4 + e] = (short)f2bf(x1[e]); }
    } else {
      a = *(const short8*)((const unsigned short*)Ap + arow * 256 + k0);
    }
#pragma unroll
    for (int tau = 0; tau < 16; ++tau) {
      int n = tau * 16 + l15;
      int kb = (k0 * 2) ^ ((n & 7) << 4);
      short8 b = *(const short8*)(wl + n * 512 + kb);
      acc[tau] = __builtin_amdgcn_mfma_f32_16x16x32_bf16(a, b, acc[tau], 0, 0, 0);
    }
  }

#pragma unroll
  for (int tau = 0; tau < 16; ++tau) {
    int n = tau * 16 + l15;
#pragma unroll
    for (int e = 0; e < 4; ++e) {
      long row = r0 + wv * 16 + g * 4 + e;
      if (OUT_F32) ((float*)outp)[row * 256 + n] = acc[tau][e];
      else         ((unsigned short*)outp)[row * 256 + n] = f2bf(acc[tau][e]);
    }
  }
}

extern "C" void kernel_launch(void* const* d_in, const int* in_sizes, int n_in,
                              void* d_out, int out_size, void* d_ws, size_t ws_size,
                              hipStream_t stream) {
  const float* x    = (const float*)d_in[0];
  const float* W_ih = (const float*)d_in[1];
  const float* W_hh = (const float*)d_in[2];
  const float* b_h  = (const float*)d_in[3];
  const float* W_ho = (const float*)d_in[4];
  const float* b_o  = (const float*)d_in[5];
  float* out  = (float*)d_out;
  float* hfin = out + (size_t)Bdim * Sdim * Hdim;

  const int gblocks = (Bdim * Sdim) / 128;                    // 1024
  const size_t half = (size_t)Bdim * Sdim * Hdim * 2;         // 64 MiB (bf16 plane)

  if (ws_size >= 2 * half) {
    unsigned short* ws1 = (unsigned short*)d_ws;              // bf16 xw
    unsigned short* ws2 = ws1 + (size_t)Bdim * Sdim * Hdim;   // bf16 h history
    gemm256<1, 0><<<gblocks, 512, 0, stream>>>(x, W_ih, b_h, ws1);   // phase 1
    rnn_scan_spec<<<2, 512, 0, stream>>>(ws1, W_hh, ws2, hfin);      // phase 2
    gemm256<0, 1><<<gblocks, 512, 0, stream>>>(ws2, W_ho, b_o, out); // phase 3
  } else {
    rnn_scan_valu_fused<<<Bdim, 256, 0, stream>>>(x, W_ih, b_h, W_hh, out, hfin);
    gemm256<1, 1><<<gblocks, 512, 0, stream>>>(out, W_ho, b_o, out); // in place
  }
}